// Round 1
// baseline (209.721 us; speedup 1.0000x reference)
//
#include <hip/hip_runtime.h>

#define BB 64
#define SS 512
#define DD 1024
#define EE 16

// ---------------------------------------------------------------------------
// Kernel 1: ragged gather + sum pool.  One thread per (b, d).
// e{1,2}pool[b,d] = sum_j embeds[b, idx[b,j], d] * mask[b,j]
// ---------------------------------------------------------------------------
__global__ void pool_kernel(const float* __restrict__ embeds,
                            const int* __restrict__ e1_idx,
                            const int* __restrict__ e2_idx,
                            const int* __restrict__ e1_mask,
                            const int* __restrict__ e2_mask,
                            float* __restrict__ pool1,
                            float* __restrict__ pool2) {
    int tid = blockIdx.x * blockDim.x + threadIdx.x;   // 0 .. B*D-1
    int b = tid >> 10;          // / DD
    int d = tid & (DD - 1);     // % DD
    const float* eb = embeds + (size_t)b * SS * DD;
    float s1 = 0.f, s2 = 0.f;
#pragma unroll
    for (int j = 0; j < EE; ++j) {
        int i1 = e1_idx[b * EE + j];
        int m1 = e1_mask[b * EE + j];
        int i2 = e2_idx[b * EE + j];
        int m2 = e2_mask[b * EE + j];
        if (m1) s1 += eb[(size_t)i1 * DD + d];
        if (m2) s2 += eb[(size_t)i2 * DD + d];
    }
    pool1[tid] = s1;
    pool2[tid] = s2;
}

// ---------------------------------------------------------------------------
// Kernel 2: logits.  One wave64 per (b, s): dot(embeds[b,s,:], pool{1,2}[b,:]).
// Each lane: 4 x float4 (16 floats) -> 64*16 = 1024 = D.  Coalesced 16B/lane.
// ---------------------------------------------------------------------------
__global__ void dots_kernel(const float* __restrict__ embeds,
                            const float* __restrict__ pool1,
                            const float* __restrict__ pool2,
                            float* __restrict__ l1,
                            float* __restrict__ l2) {
    int gtid = blockIdx.x * blockDim.x + threadIdx.x;
    int wave = gtid >> 6;       // global wave id = b*S + s
    int lane = threadIdx.x & 63;
    int b = wave >> 9;          // / SS

    const float4* row = (const float4*)(embeds + (size_t)wave * DD);
    const float4* p1  = (const float4*)(pool1 + (size_t)b * DD);
    const float4* p2  = (const float4*)(pool2 + (size_t)b * DD);

    float a1 = 0.f, a2 = 0.f;
#pragma unroll
    for (int k = 0; k < 4; ++k) {
        int idx = k * 64 + lane;
        float4 e  = row[idx];
        float4 q1 = p1[idx];
        float4 q2 = p2[idx];
        a1 += e.x * q1.x + e.y * q1.y + e.z * q1.z + e.w * q1.w;
        a2 += e.x * q2.x + e.y * q2.y + e.z * q2.z + e.w * q2.w;
    }
#pragma unroll
    for (int off = 32; off > 0; off >>= 1) {
        a1 += __shfl_down(a1, off, 64);
        a2 += __shfl_down(a2, off, 64);
    }
    if (lane == 0) {
        l1[wave] = a1;
        l2[wave] = a2;
    }
}

// ---------------------------------------------------------------------------
// Kernel 3: softmax over S for both logit sets + average.
// One block (256 threads) per b; each thread owns elements t and t+256.
// ---------------------------------------------------------------------------
__global__ void softmax_kernel(const float* __restrict__ l1,
                               const float* __restrict__ l2,
                               float* __restrict__ out) {
    __shared__ float sm[4];
    int b = blockIdx.x;
    int t = threadIdx.x;
    int wid = t >> 6, lane = t & 63;

    float x1a = l1[b * SS + t],       x2a = l2[b * SS + t];
    float x1b = l1[b * SS + t + 256], x2b = l2[b * SS + t + 256];

    // ---- max over both streams at once (per-stream maxes kept separate) ----
    // reduce m1
    float v = fmaxf(x1a, x1b);
#pragma unroll
    for (int off = 32; off > 0; off >>= 1) v = fmaxf(v, __shfl_down(v, off, 64));
    if (lane == 0) sm[wid] = v;
    __syncthreads();
    float m1 = fmaxf(fmaxf(sm[0], sm[1]), fmaxf(sm[2], sm[3]));
    __syncthreads();
    // reduce m2
    v = fmaxf(x2a, x2b);
#pragma unroll
    for (int off = 32; off > 0; off >>= 1) v = fmaxf(v, __shfl_down(v, off, 64));
    if (lane == 0) sm[wid] = v;
    __syncthreads();
    float m2 = fmaxf(fmaxf(sm[0], sm[1]), fmaxf(sm[2], sm[3]));
    __syncthreads();

    float e1a = __expf(x1a - m1), e1b = __expf(x1b - m1);
    float e2a = __expf(x2a - m2), e2b = __expf(x2b - m2);

    // sum 1
    v = e1a + e1b;
#pragma unroll
    for (int off = 32; off > 0; off >>= 1) v += __shfl_down(v, off, 64);
    if (lane == 0) sm[wid] = v;
    __syncthreads();
    float s1 = sm[0] + sm[1] + sm[2] + sm[3];
    __syncthreads();
    // sum 2
    v = e2a + e2b;
#pragma unroll
    for (int off = 32; off > 0; off >>= 1) v += __shfl_down(v, off, 64);
    if (lane == 0) sm[wid] = v;
    __syncthreads();
    float s2 = sm[0] + sm[1] + sm[2] + sm[3];

    float r1 = 1.f / s1, r2 = 1.f / s2;
    out[b * SS + t]       = 0.5f * (e1a * r1 + e2a * r2);
    out[b * SS + t + 256] = 0.5f * (e1b * r1 + e2b * r2);
}

// ---------------------------------------------------------------------------
extern "C" void kernel_launch(void* const* d_in, const int* in_sizes, int n_in,
                              void* d_out, int out_size, void* d_ws, size_t ws_size,
                              hipStream_t stream) {
    const float* embeds  = (const float*)d_in[0];
    const int*   e1_idx  = (const int*)d_in[1];
    const int*   e2_idx  = (const int*)d_in[2];
    const int*   e1_mask = (const int*)d_in[3];
    const int*   e2_mask = (const int*)d_in[4];
    float* out = (float*)d_out;

    float* ws    = (float*)d_ws;
    float* pool1 = ws;                        // B*D
    float* pool2 = ws + BB * DD;              // B*D
    float* l1    = ws + 2 * BB * DD;          // B*S
    float* l2    = ws + 2 * BB * DD + BB * SS;// B*S

    pool_kernel<<<BB * DD / 256, 256, 0, stream>>>(embeds, e1_idx, e2_idx,
                                                   e1_mask, e2_mask, pool1, pool2);
    dots_kernel<<<BB * SS / 4, 256, 0, stream>>>(embeds, pool1, pool2, l1, l2);
    softmax_kernel<<<BB, 256, 0, stream>>>(l1, l2, out);
}

// Round 2
// 206.102 us; speedup vs baseline: 1.0176x; 1.0176x over previous
//
#include <hip/hip_runtime.h>

#define BB 64
#define SS 512
#define DD 1024
#define EE 16

// ---------------------------------------------------------------------------
// Kernel 1: ragged gather + sum pool.  One block per b, 256 threads.
// Each thread owns 4 consecutive d (one float4). Indices/masks staged in LDS.
// ---------------------------------------------------------------------------
__global__ void pool_kernel(const float* __restrict__ embeds,
                            const int* __restrict__ e1_idx,
                            const int* __restrict__ e2_idx,
                            const int* __restrict__ e1_mask,
                            const int* __restrict__ e2_mask,
                            float* __restrict__ pool1,
                            float* __restrict__ pool2) {
    __shared__ int si1[EE], sm1[EE], si2[EE], sm2[EE];
    int b = blockIdx.x;
    int t = threadIdx.x;                  // 0..255, owns d = 4t..4t+3
    if (t < EE) {
        si1[t] = e1_idx[b * EE + t];
        sm1[t] = e1_mask[b * EE + t];
        si2[t] = e2_idx[b * EE + t];
        sm2[t] = e2_mask[b * EE + t];
    }
    __syncthreads();

    const float* eb = embeds + (size_t)b * SS * DD;
    float4 s1 = make_float4(0.f, 0.f, 0.f, 0.f);
    float4 s2 = make_float4(0.f, 0.f, 0.f, 0.f);
#pragma unroll
    for (int j = 0; j < EE; ++j) {
        if (sm1[j]) {            // wave-uniform branch (same for whole block)
            float4 v = ((const float4*)(eb + (size_t)si1[j] * DD))[t];
            s1.x += v.x; s1.y += v.y; s1.z += v.z; s1.w += v.w;
        }
        if (sm2[j]) {
            float4 v = ((const float4*)(eb + (size_t)si2[j] * DD))[t];
            s2.x += v.x; s2.y += v.y; s2.z += v.z; s2.w += v.w;
        }
    }
    ((float4*)(pool1 + (size_t)b * DD))[t] = s1;
    ((float4*)(pool2 + (size_t)b * DD))[t] = s2;
}

// ---------------------------------------------------------------------------
// Kernel 2: logits. One wave64 per PAIR of rows (b,2w),(b,2w+1).
// Per k-iter each lane loads 2 embed float4s + 2 pool float4s (pool traffic
// halved vs 1 row/wave). 4 running dots -> shuffle butterfly -> lane0 writes.
// ---------------------------------------------------------------------------
__global__ void dots_kernel(const float* __restrict__ embeds,
                            const float* __restrict__ pool1,
                            const float* __restrict__ pool2,
                            float* __restrict__ l1,
                            float* __restrict__ l2) {
    int gtid = blockIdx.x * blockDim.x + threadIdx.x;
    int wave = gtid >> 6;        // 0 .. B*S/2-1
    int lane = threadIdx.x & 63;
    int s0 = wave * 2;           // first row of the pair (global row id b*S+s)
    int b = s0 >> 9;             // / SS

    const float4* row0 = (const float4*)(embeds + (size_t)s0 * DD);
    const float4* row1 = (const float4*)(embeds + (size_t)(s0 + 1) * DD);
    const float4* p1   = (const float4*)(pool1 + (size_t)b * DD);
    const float4* p2   = (const float4*)(pool2 + (size_t)b * DD);

    float a10 = 0.f, a20 = 0.f, a11 = 0.f, a21 = 0.f;
#pragma unroll
    for (int k = 0; k < 4; ++k) {
        int idx = k * 64 + lane;
        float4 e0 = row0[idx];
        float4 e1 = row1[idx];
        float4 q1 = p1[idx];
        float4 q2 = p2[idx];
        a10 += e0.x * q1.x + e0.y * q1.y + e0.z * q1.z + e0.w * q1.w;
        a20 += e0.x * q2.x + e0.y * q2.y + e0.z * q2.z + e0.w * q2.w;
        a11 += e1.x * q1.x + e1.y * q1.y + e1.z * q1.z + e1.w * q1.w;
        a21 += e1.x * q2.x + e1.y * q2.y + e1.z * q2.z + e1.w * q2.w;
    }
#pragma unroll
    for (int off = 32; off > 0; off >>= 1) {
        a10 += __shfl_down(a10, off, 64);
        a20 += __shfl_down(a20, off, 64);
        a11 += __shfl_down(a11, off, 64);
        a21 += __shfl_down(a21, off, 64);
    }
    if (lane == 0) {
        ((float2*)l1)[wave] = make_float2(a10, a11);
        ((float2*)l2)[wave] = make_float2(a20, a21);
    }
}

// ---------------------------------------------------------------------------
// Kernel 3: softmax over S for both logit sets + average.
// One block (256 threads) per b; each thread owns elements t and t+256.
// Both streams reduced per LDS round (2 rounds total).
// ---------------------------------------------------------------------------
__global__ void softmax_kernel(const float* __restrict__ l1,
                               const float* __restrict__ l2,
                               float* __restrict__ out) {
    __shared__ float sm[8];
    int b = blockIdx.x;
    int t = threadIdx.x;
    int wid = t >> 6, lane = t & 63;

    float x1a = l1[b * SS + t],       x2a = l2[b * SS + t];
    float x1b = l1[b * SS + t + 256], x2b = l2[b * SS + t + 256];

    // ---- max reduction, both streams ----
    float v1 = fmaxf(x1a, x1b);
    float v2 = fmaxf(x2a, x2b);
#pragma unroll
    for (int off = 32; off > 0; off >>= 1) {
        v1 = fmaxf(v1, __shfl_down(v1, off, 64));
        v2 = fmaxf(v2, __shfl_down(v2, off, 64));
    }
    if (lane == 0) { sm[wid] = v1; sm[4 + wid] = v2; }
    __syncthreads();
    float m1 = fmaxf(fmaxf(sm[0], sm[1]), fmaxf(sm[2], sm[3]));
    float m2 = fmaxf(fmaxf(sm[4], sm[5]), fmaxf(sm[6], sm[7]));
    __syncthreads();

    float e1a = __expf(x1a - m1), e1b = __expf(x1b - m1);
    float e2a = __expf(x2a - m2), e2b = __expf(x2b - m2);

    // ---- sum reduction, both streams ----
    v1 = e1a + e1b;
    v2 = e2a + e2b;
#pragma unroll
    for (int off = 32; off > 0; off >>= 1) {
        v1 += __shfl_down(v1, off, 64);
        v2 += __shfl_down(v2, off, 64);
    }
    if (lane == 0) { sm[wid] = v1; sm[4 + wid] = v2; }
    __syncthreads();
    float s1 = sm[0] + sm[1] + sm[2] + sm[3];
    float s2 = sm[4] + sm[5] + sm[6] + sm[7];

    float r1 = 1.f / s1, r2 = 1.f / s2;
    out[b * SS + t]       = 0.5f * (e1a * r1 + e2a * r2);
    out[b * SS + t + 256] = 0.5f * (e1b * r1 + e2b * r2);
}

// ---------------------------------------------------------------------------
extern "C" void kernel_launch(void* const* d_in, const int* in_sizes, int n_in,
                              void* d_out, int out_size, void* d_ws, size_t ws_size,
                              hipStream_t stream) {
    const float* embeds  = (const float*)d_in[0];
    const int*   e1_idx  = (const int*)d_in[1];
    const int*   e2_idx  = (const int*)d_in[2];
    const int*   e1_mask = (const int*)d_in[3];
    const int*   e2_mask = (const int*)d_in[4];
    float* out = (float*)d_out;

    float* ws    = (float*)d_ws;
    float* pool1 = ws;                         // B*D
    float* pool2 = ws + BB * DD;               // B*D
    float* l1    = ws + 2 * BB * DD;           // B*S
    float* l2    = ws + 2 * BB * DD + BB * SS; // B*S

    pool_kernel<<<BB, 256, 0, stream>>>(embeds, e1_idx, e2_idx,
                                        e1_mask, e2_mask, pool1, pool2);
    dots_kernel<<<BB * SS / 8, 256, 0, stream>>>(embeds, pool1, pool2, l1, l2);
    softmax_kernel<<<BB, 256, 0, stream>>>(l1, l2, out);
}